// Round 5
// baseline (251.777 us; speedup 1.0000x reference)
//
#include <hip/hip_runtime.h>

// StrictProjectionBlock: per-3x3-matrix Frobenius normalize + 4 Newton-Schulz
// layers. dur_us = ~173us harness poison fills (fixed) + kernel.
// History:
//  R4 block-sync LDS:        88us  VALU 36%  occ 63%  VGPR 20
//  R5 w12 DMA:               FAILED (unverified 12B global_load_lds width)
//  R6 persistent reg-staged: 88us  VALU 35%  occ 58%  VGPR 32 (prefetch sunk)
//  R7 no-LDS direct strided: 87us  VALU 35%  occ 66%  VGPR 20
//  R1->R7 cut VALU work 30% (VALUBusy 52->35%) with ZERO time change, and
//  fills hit 6.6 TB/s at 9% occupancy -> not VALU-, BW-, churn-, or
//  coalescing-bound. Every pipe ~30% = latency-bound, bytes-in-flight
//  deficit. Shared invariant of all five variants: ONE matrix per thread =
//  one 2304B load burst per wave, then a ~1200cy dependent chain. VGPR=20
//  shows the compiler schedules for minimal liveness -> near-zero MLP.
//
// R8: 4 matrices per thread; ALL 12 loads issued before any compute and
// PINNED with __builtin_amdgcn_sched_barrier(0) (R6 showed the scheduler
// otherwise sinks loads to their uses). 9.2KB in flight per wave (4x), four
// independent compute chains for intra-wave ILP. __launch_bounds__(256,4)
// (<=128 VGPR; ~36 loaded floats must live across the barrier). Stores
// normal (L2-merged, proven equivalent to NT in R1-R7).
// Tail: 4,000,000 = 3906*1024 + 256 -> last block does 1 matrix/thread
// (block-uniform branch).
// Math unchanged (R2): Q' = Q*M, M = (0.5N-1.5I)N + 2I, symmetric.

#define NLAYERS 4

// 4-byte-aligned float4: legal dword-aligned global_load_dwordx4.
typedef float v4fu __attribute__((ext_vector_type(4), aligned(4)));

__device__ __forceinline__ void load9(const float* __restrict__ src, float q[9]) {
    const v4fu a = *(const v4fu*)(src);
    const v4fu b = *(const v4fu*)(src + 4);
    q[0] = a.x; q[1] = a.y; q[2] = a.z; q[3] = a.w;
    q[4] = b.x; q[5] = b.y; q[6] = b.z; q[7] = b.w;
    q[8] = src[8];
}

__device__ __forceinline__ void store9(float* __restrict__ dst, const float q[9]) {
    v4fu a, b;
    a.x = q[0]; a.y = q[1]; a.z = q[2]; a.w = q[3];
    b.x = q[4]; b.y = q[5]; b.z = q[6]; b.w = q[7];
    *(v4fu*)(dst)     = a;
    *(v4fu*)(dst + 4) = b;
    dst[8] = q[8];
}

__device__ __forceinline__ void ns_chain(float q[9]) {
    // Frobenius normalize
    float s = 0.f;
#pragma unroll
    for (int j = 0; j < 9; ++j) s = __builtin_fmaf(q[j], q[j], s);
    const float inv = rsqrtf(s);
#pragma unroll
    for (int j = 0; j < 9; ++j) q[j] *= inv;

    // 4 Newton-Schulz layers: Q <- Q * ((0.5N - 1.5I)N + 2I)
#pragma unroll
    for (int layer = 0; layer < NLAYERS; ++layer) {
        const float n00 = q[0]*q[0] + q[3]*q[3] + q[6]*q[6];
        const float n01 = q[0]*q[1] + q[3]*q[4] + q[6]*q[7];
        const float n02 = q[0]*q[2] + q[3]*q[5] + q[6]*q[8];
        const float n11 = q[1]*q[1] + q[4]*q[4] + q[7]*q[7];
        const float n12 = q[1]*q[2] + q[4]*q[5] + q[7]*q[8];
        const float n22 = q[2]*q[2] + q[5]*q[5] + q[8]*q[8];

        const float a00 = __builtin_fmaf(0.5f, n00, -1.5f);
        const float a11 = __builtin_fmaf(0.5f, n11, -1.5f);
        const float a22 = __builtin_fmaf(0.5f, n22, -1.5f);
        const float a01 = 0.5f * n01;
        const float a02 = 0.5f * n02;
        const float a12 = 0.5f * n12;

        const float m00 = __builtin_fmaf(a00,n00, __builtin_fmaf(a01,n01, __builtin_fmaf(a02,n02, 2.0f)));
        const float m01 = __builtin_fmaf(a00,n01, __builtin_fmaf(a01,n11, a02*n12));
        const float m02 = __builtin_fmaf(a00,n02, __builtin_fmaf(a01,n12, a02*n22));
        const float m11 = __builtin_fmaf(a01,n01, __builtin_fmaf(a11,n11, __builtin_fmaf(a12,n12, 2.0f)));
        const float m12 = __builtin_fmaf(a01,n02, __builtin_fmaf(a11,n12, a12*n22));
        const float m22 = __builtin_fmaf(a02,n02, __builtin_fmaf(a12,n12, __builtin_fmaf(a22,n22, 2.0f)));

        float qn[9];
#pragma unroll
        for (int i = 0; i < 3; ++i) {
            const float q0 = q[3*i], q1 = q[3*i+1], q2 = q[3*i+2];
            qn[3*i+0] = __builtin_fmaf(q0, m00, __builtin_fmaf(q1, m01, q2 * m02));
            qn[3*i+1] = __builtin_fmaf(q0, m01, __builtin_fmaf(q1, m11, q2 * m12));
            qn[3*i+2] = __builtin_fmaf(q0, m02, __builtin_fmaf(q1, m12, q2 * m22));
        }
#pragma unroll
        for (int j = 0; j < 9; ++j) q[j] = qn[j];
    }
}

__global__ __launch_bounds__(256, 4) void
proj_kernel(const float* __restrict__ x, float* __restrict__ out, int nfull) {
    const int tid = threadIdx.x;

    if ((int)blockIdx.x < nfull) {
        // ---- main: 4 matrices/thread, strided by 256 within the block ----
        const long long base = (long long)blockIdx.x * 1024 + tid;
        float q0[9], q1[9], q2[9], q3[9];
        load9(x + base * 9,          q0);
        load9(x + (base + 256) * 9,  q1);
        load9(x + (base + 512) * 9,  q2);
        load9(x + (base + 768) * 9,  q3);
        // Pin: all 12 VMEM loads issue BEFORE any compute (no sinking).
        __builtin_amdgcn_sched_barrier(0);
        ns_chain(q0);
        ns_chain(q1);
        ns_chain(q2);
        ns_chain(q3);
        store9(out + base * 9,         q0);
        store9(out + (base + 256) * 9, q1);
        store9(out + (base + 512) * 9, q2);
        store9(out + (base + 768) * 9, q3);
    } else {
        // ---- tail block: exactly 256 matrices, one per thread ----
        const long long m = (long long)nfull * 1024 + tid;
        float q[9];
        load9(x + m * 9, q);
        ns_chain(q);
        store9(out + m * 9, q);
    }
}

extern "C" void kernel_launch(void* const* d_in, const int* in_sizes, int n_in,
                              void* d_out, int out_size, void* d_ws, size_t ws_size,
                              hipStream_t stream) {
    const float* x = (const float*)d_in[0];
    float* out = (float*)d_out;
    const int nmat = in_sizes[0] / 9;        // 4,000,000
    const int nfull = nmat / 1024;           // 3906 full blocks
    const int rem = nmat - nfull * 1024;     // 256 -> one tail block
    const int blocks = nfull + (rem ? 1 : 0);
    proj_kernel<<<blocks, 256, 0, stream>>>(x, out, nfull);
}